// Round 2
// baseline (609.364 us; speedup 1.0000x reference)
//
#include <hip/hip_runtime.h>
#include <stdint.h>

typedef float f32x4 __attribute__((ext_vector_type(4)));
typedef __bf16 bf16x8 __attribute__((ext_vector_type(8)));
typedef unsigned short u16x8 __attribute__((ext_vector_type(8)));

__device__ __forceinline__ unsigned short f2bf(float f) {
  union { float f; unsigned u; } x; x.f = f;
  unsigned r = x.u + 0x7fffu + ((x.u >> 16) & 1u);
  return (unsigned short)(r >> 16);
}
__device__ __forceinline__ float bf2f(unsigned short u) {
  union { unsigned u; float f; } x; x.u = ((unsigned)u) << 16;
  return x.f;
}
__device__ __forceinline__ void async_copy16(void* lds, const void* g) {
  __builtin_amdgcn_global_load_lds(
      (const unsigned int __attribute__((address_space(1)))*)g,
      (unsigned int __attribute__((address_space(3)))*)lds, 16, 0, 0);
}
__device__ __forceinline__ f32x4 mfma16(bf16x8 a, bf16x8 b, f32x4 c) {
  return __builtin_amdgcn_mfma_f32_16x16x32_bf16(a, b, c, 0, 0, 0);
}

// ---------------- fp32 -> bf16 convert ----------------
__global__ __launch_bounds__(256) void cvt_f32_bf16(
    const float* __restrict__ in, unsigned short* __restrict__ out, int n8) {
  int stride = gridDim.x * blockDim.x;
  for (int i = blockIdx.x * blockDim.x + threadIdx.x; i < n8; i += stride) {
    const float4* p = (const float4*)in + (size_t)i * 2;
    float4 a = p[0], b = p[1];
    u16x8 o;
    o[0] = f2bf(a.x); o[1] = f2bf(a.y); o[2] = f2bf(a.z); o[3] = f2bf(a.w);
    o[4] = f2bf(b.x); o[5] = f2bf(b.y); o[6] = f2bf(b.z); o[7] = f2bf(b.w);
    *((u16x8*)out + i) = o;
  }
}

// ---------------- RoPE cos/sin table: [2048][64] float2 (cos,sin) ----------------
__global__ __launch_bounds__(256) void rope_table(float2* __restrict__ cs) {
  int idx = blockIdx.x * 256 + threadIdx.x;   // 2048*64 = 131072
  if (idx >= 2048 * 64) return;
  int t = idx >> 6, j = idx & 63;
  // inv_freq = 10000^(-j/64) = exp(-ln(10000)/64 * j)
  float inv = expf(-0.14391156516026f * (float)j);
  float ang = (float)t * inv;
  cs[idx] = make_float2(cosf(ang), sinf(ang));
}

// ---------------- GEMM: C[M,N] = A[M,K] * Bt[N,K]^T, bf16 in, bf16/f32 out ----------------
// 128x128 tile, BK=32, 256 threads (4 waves, 2x2 wave grid), dbuf LDS staging
// via global_load_lds(16B); XOR slot swizzle (slot ^= row&3) on 64B rows.
#define BM 128
#define BN 128
#define BK 32

template <bool OUT_F32>
__global__ __launch_bounds__(256, 2) void gemm_bt(
    const unsigned short* __restrict__ A, const unsigned short* __restrict__ Bt,
    void* __restrict__ Cout, int M, int N, int K) {
  __shared__ unsigned short sA[2][BM * BK];
  __shared__ unsigned short sB[2][BN * BK];
  const int tid = threadIdx.x;
  const int w = tid >> 6, l = tid & 63;
  const int m0 = blockIdx.y * BM, n0 = blockIdx.x * BN;
  const int wr = w >> 1, wc = w & 1;
  const int g = l >> 4, lr = l & 15;

  f32x4 acc[4][4];
#pragma unroll
  for (int i = 0; i < 4; ++i)
#pragma unroll
    for (int j = 0; j < 4; ++j) acc[i][j] = f32x4{0.f, 0.f, 0.f, 0.f};

  const int rl = l >> 2, ps = l & 3;
  auto stage = [&](int buf, int k0) {
#pragma unroll
    for (int i = 0; i < 2; ++i) {
      int region = w + i * 4;                 // 8 regions of 16 rows each
      int row = region * 16 + rl;
      int s = ps ^ (row & 3);                 // pre-swizzled global source
      async_copy16(&sA[buf][region * 16 * BK],
                   A + (size_t)(m0 + row) * K + k0 + s * 8);
      async_copy16(&sB[buf][region * 16 * BK],
                   Bt + (size_t)(n0 + row) * K + k0 + s * 8);
    }
  };

  stage(0, 0);
  int cur = 0;
  const int NK = K / BK;
  for (int kt = 0; kt < NK; ++kt) {
    asm volatile("s_waitcnt vmcnt(0)" ::: "memory");
    __syncthreads();
    if (kt + 1 < NK) stage(cur ^ 1, (kt + 1) * BK);

    bf16x8 af[4], bfr[4];
#pragma unroll
    for (int mi = 0; mi < 4; ++mi) {
      int row = wr * 64 + mi * 16 + lr;
      af[mi] = *(const bf16x8*)&sA[cur][row * BK + ((g ^ (row & 3)) << 3)];
    }
#pragma unroll
    for (int ni = 0; ni < 4; ++ni) {
      int row = wc * 64 + ni * 16 + lr;
      bfr[ni] = *(const bf16x8*)&sB[cur][row * BK + ((g ^ (row & 3)) << 3)];
    }
#pragma unroll
    for (int mi = 0; mi < 4; ++mi)
#pragma unroll
      for (int ni = 0; ni < 4; ++ni)
        acc[mi][ni] = mfma16(af[mi], bfr[ni], acc[mi][ni]);
    __syncthreads();
    cur ^= 1;
  }

#pragma unroll
  for (int mi = 0; mi < 4; ++mi)
#pragma unroll
    for (int ni = 0; ni < 4; ++ni) {
      int col = n0 + wc * 64 + ni * 16 + lr;
#pragma unroll
      for (int jr = 0; jr < 4; ++jr) {
        int row = m0 + wr * 64 + mi * 16 + g * 4 + jr;
        float v = acc[mi][ni][jr];
        if (OUT_F32)
          ((float*)Cout)[(size_t)row * N + col] = v;
        else
          ((unsigned short*)Cout)[(size_t)row * N + col] = f2bf(v);
      }
    }
}

// ---------------- RoPE + scatter: qkv[4096][6144] -> Q,K [bh][T][128], Vt [bh][128][T] ----------------
__global__ __launch_bounds__(256) void prep_rope(
    const unsigned short* __restrict__ qkv, const float2* __restrict__ cs,
    unsigned short* __restrict__ Q, unsigned short* __restrict__ K,
    unsigned short* __restrict__ Vt) {
  const int tt = blockIdx.x, h = blockIdx.y, b = blockIdx.z;
  const int t0 = tt * 64;
  const int tid = threadIdx.x;
  __shared__ unsigned short vt[64][130];   // +2 pad: conflict-free column reads

#pragma unroll 4
  for (int i = 0; i < 32; ++i) {
    int lin = i * 256 + tid;             // 64 rows x 128 dims
    int r = lin >> 7, j = lin & 127;
    int t = t0 + r;
    int jj = j & 63;
    size_t rowbase = ((size_t)(b * 2048 + t)) * 6144 + h * 128;
    float2 c_s = cs[t * 64 + jj];
    float q1 = bf2f(qkv[rowbase + 2 * jj]);
    float q2 = bf2f(qkv[rowbase + 2 * jj + 1]);
    float k1 = bf2f(qkv[rowbase + 2048 + 2 * jj]);
    float k2 = bf2f(qkv[rowbase + 2048 + 2 * jj + 1]);
    float qo = (j < 64) ? (q1 * c_s.x - q2 * c_s.y) : (q1 * c_s.y + q2 * c_s.x);
    float ko = (j < 64) ? (k1 * c_s.x - k2 * c_s.y) : (k1 * c_s.y + k2 * c_s.x);
    size_t obase = ((size_t)((b * 16 + h) * 2048 + t)) * 128 + j;
    Q[obase] = f2bf(qo);
    K[obase] = f2bf(ko);
    vt[r][j] = qkv[rowbase + 4096 + j];
  }
  __syncthreads();
  size_t vbase = ((size_t)((b * 16 + h) * 128)) * 2048 + t0;
#pragma unroll 4
  for (int i = 0; i < 32; ++i) {
    int lin = i * 256 + tid;
    int d = lin >> 6, c = lin & 63;
    Vt[vbase + (size_t)d * 2048 + c] = vt[c][d];
  }
}

// ---------------- causal flash attention ----------------
// block: (qt, bh). 256 thr = 4 waves x 32 q-rows = 128-row Q tile; KV tile 64.
// sK [64][128] swz slot^=(kv&15); sV=[128][64] (V^T) swz slot^=(d&7); sP per-wave [32][64] swz slot^=(q&7).
__global__ __launch_bounds__(256) void attn_fwd(
    const unsigned short* __restrict__ Q, const unsigned short* __restrict__ K,
    const unsigned short* __restrict__ Vt, unsigned short* __restrict__ AO) {
  const int qt = 15 - (int)blockIdx.x;       // heavy tiles first
  const int bh = blockIdx.y;
  const int b = bh >> 4, h = bh & 15;
  __shared__ unsigned short sK[64 * 128];
  __shared__ unsigned short sV[128 * 64];
  __shared__ unsigned short sP[4][32 * 64];
  const int tid = threadIdx.x, w = tid >> 6, l = tid & 63;
  const int g = l >> 4, lr = l & 15;
  const int q0 = qt * 128 + w * 32;
  const size_t qkbase = (size_t)bh * 2048 * 128;
  const size_t vbase = (size_t)bh * 128 * 2048;

  bf16x8 qf[2][4];
#pragma unroll
  for (int mi = 0; mi < 2; ++mi)
#pragma unroll
    for (int kc = 0; kc < 4; ++kc)
      qf[mi][kc] = *(const bf16x8*)(Q + qkbase +
                    (size_t)(q0 + mi * 16 + lr) * 128 + kc * 32 + g * 8);

  f32x4 of[2][8];
  float mrow[2][4], lsum[2][4];
#pragma unroll
  for (int mi = 0; mi < 2; ++mi) {
#pragma unroll
    for (int nd = 0; nd < 8; ++nd) of[mi][nd] = f32x4{0.f, 0.f, 0.f, 0.f};
#pragma unroll
    for (int jr = 0; jr < 4; ++jr) { mrow[mi][jr] = -1e30f; lsum[mi][jr] = 0.f; }
  }
  const float scale = 0.08838834764831845f;  // 1/sqrt(128)

  const int NT = 2 * qt + 2;
  for (int kt = 0; kt < NT; ++kt) {
    // ---- stage K (64x128) and V^T (128x64), pre-swizzled sources ----
    {
      const int rl4 = l >> 4, ps16 = l & 15;
      const int rl8 = l >> 3, ps8 = l & 7;
#pragma unroll
      for (int i = 0; i < 4; ++i) {
        int region = w * 4 + i;
        int kv = region * 4 + rl4;
        int s1 = ps16 ^ (kv & 15);
        async_copy16(&sK[region * 4 * 128],
                     K + qkbase + (size_t)(kt * 64 + kv) * 128 + s1 * 8);
        int d = region * 8 + rl8;
        int s2 = ps8 ^ (d & 7);
        async_copy16(&sV[region * 8 * 64],
                     Vt + vbase + (size_t)d * 2048 + kt * 64 + s2 * 8);
      }
    }
    asm volatile("s_waitcnt vmcnt(0)" ::: "memory");
    __syncthreads();

    // ---- S = Q K^T ----
    f32x4 sacc[2][4];
#pragma unroll
    for (int mi = 0; mi < 2; ++mi)
#pragma unroll
      for (int ni = 0; ni < 4; ++ni) sacc[mi][ni] = f32x4{0.f, 0.f, 0.f, 0.f};
#pragma unroll
    for (int kc = 0; kc < 4; ++kc) {
      bf16x8 kf[4];
#pragma unroll
      for (int ni = 0; ni < 4; ++ni) {
        int kv = ni * 16 + lr;
        kf[ni] = *(const bf16x8*)&sK[kv * 128 + (((kc * 4 + g) ^ (kv & 15)) << 3)];
      }
#pragma unroll
      for (int mi = 0; mi < 2; ++mi)
#pragma unroll
        for (int ni = 0; ni < 4; ++ni)
          sacc[mi][ni] = mfma16(qf[mi][kc], kf[ni], sacc[mi][ni]);
    }

    // ---- online softmax (wave-parallel, 16-lane groups) ----
    const bool diag = (kt >= 2 * qt);
#pragma unroll
    for (int mi = 0; mi < 2; ++mi) {
      float pm[4] = {-1e30f, -1e30f, -1e30f, -1e30f};
#pragma unroll
      for (int ni = 0; ni < 4; ++ni)
#pragma unroll
        for (int jr = 0; jr < 4; ++jr) {
          float s = sacc[mi][ni][jr] * scale;
          if (diag) {
            int kvg = kt * 64 + ni * 16 + lr;
            int qg = q0 + mi * 16 + g * 4 + jr;
            if (kvg > qg) s = -1e30f;
          }
          sacc[mi][ni][jr] = s;
          pm[jr] = fmaxf(pm[jr], s);
        }
#pragma unroll
      for (int jr = 0; jr < 4; ++jr) {
        float v = pm[jr];
        v = fmaxf(v, __shfl_xor(v, 1));
        v = fmaxf(v, __shfl_xor(v, 2));
        v = fmaxf(v, __shfl_xor(v, 4));
        v = fmaxf(v, __shfl_xor(v, 8));
        float mnew = fmaxf(mrow[mi][jr], v);
        float fac = __expf(mrow[mi][jr] - mnew);
        mrow[mi][jr] = mnew;
        float rsum = 0.f;
#pragma unroll
        for (int ni = 0; ni < 4; ++ni) {
          float p = __expf(sacc[mi][ni][jr] - mnew);
          sacc[mi][ni][jr] = p;
          rsum += p;
        }
        rsum += __shfl_xor(rsum, 1);
        rsum += __shfl_xor(rsum, 2);
        rsum += __shfl_xor(rsum, 4);
        rsum += __shfl_xor(rsum, 8);
        lsum[mi][jr] = lsum[mi][jr] * fac + rsum;
#pragma unroll
        for (int nd = 0; nd < 8; ++nd) of[mi][nd][jr] *= fac;
      }
      // write P (bf16) to wave-private swizzled LDS
#pragma unroll
      for (int ni = 0; ni < 4; ++ni)
#pragma unroll
        for (int jr = 0; jr < 4; ++jr) {
          int q = mi * 16 + g * 4 + jr;
          int kv = ni * 16 + lr;
          sP[w][q * 64 + (((kv >> 3) ^ (q & 7)) << 3) + (kv & 7)] =
              f2bf(sacc[mi][ni][jr]);
        }
    }

    // ---- O += P V ----
#pragma unroll
    for (int kc = 0; kc < 2; ++kc) {
      bf16x8 pa[2];
#pragma unroll
      for (int mi = 0; mi < 2; ++mi) {
        int q = mi * 16 + lr;
        pa[mi] = *(const bf16x8*)&sP[w][q * 64 + (((kc * 4 + g) ^ (q & 7)) << 3)];
      }
#pragma unroll
      for (int nd = 0; nd < 8; ++nd) {
        int d = nd * 16 + lr;
        bf16x8 vb = *(const bf16x8*)&sV[d * 64 + (((kc * 4 + g) ^ (d & 7)) << 3)];
#pragma unroll
        for (int mi = 0; mi < 2; ++mi) of[mi][nd] = mfma16(pa[mi], vb, of[mi][nd]);
      }
    }
    __syncthreads();
  }

  // ---- epilogue: normalize, write AO [B][T][C] bf16 ----
#pragma unroll
  for (int mi = 0; mi < 2; ++mi)
#pragma unroll
    for (int nd = 0; nd < 8; ++nd)
#pragma unroll
      for (int jr = 0; jr < 4; ++jr) {
        int qrow = q0 + mi * 16 + g * 4 + jr;
        int d = nd * 16 + lr;
        float v = of[mi][nd][jr] / lsum[mi][jr];
        AO[(size_t)(b * 2048 + qrow) * 2048 + h * 128 + d] = f2bf(v);
      }
}

// ---------------- launch ----------------
extern "C" void kernel_launch(void* const* d_in, const int* in_sizes, int n_in,
                              void* d_out, int out_size, void* d_ws, size_t ws_size,
                              hipStream_t stream) {
  (void)in_sizes; (void)n_in; (void)out_size; (void)ws_size;
  const float* x = (const float*)d_in[0];
  const float* wqkv = (const float*)d_in[1];
  const float* wproj = (const float*)d_in[2];

  char* ws = (char*)d_ws;
  unsigned short* WPROJB = (unsigned short*)(ws + 0);            //  8.4 MB
  unsigned short* XB     = (unsigned short*)(ws + 8388608);      // 16.8 MB (reused as AO)
  unsigned short* WQKVB  = (unsigned short*)(ws + 25165824);     // 25.2 MB (reused as Q)
  unsigned short* QKV    = (unsigned short*)(ws + 50331648);     // 50.3 MB
  unsigned short* Kr     = (unsigned short*)(ws + 100663296);    // 16.8 MB
  unsigned short* Vt     = (unsigned short*)(ws + 117440512);    // 16.8 MB
  float2*         CS     = (float2*)(ws + 134217728);            //  1.0 MB
  unsigned short* AO = XB;
  unsigned short* Qr = WQKVB;

  rope_table<<<512, 256, 0, stream>>>(CS);
  cvt_f32_bf16<<<2048, 256, 0, stream>>>(x, XB, 8388608 / 8);
  cvt_f32_bf16<<<2048, 256, 0, stream>>>(wqkv, WQKVB, 12582912 / 8);
  cvt_f32_bf16<<<1024, 256, 0, stream>>>(wproj, WPROJB, 4194304 / 8);
  // qkv = x @ w_qkv^T : [4096,2048] x [6144,2048]^T
  gemm_bt<false><<<dim3(48, 32), 256, 0, stream>>>(XB, WQKVB, QKV, 4096, 6144, 2048);
  prep_rope<<<dim3(32, 16, 2), 256, 0, stream>>>(QKV, CS, Qr, Kr, Vt);
  attn_fwd<<<dim3(16, 32), 256, 0, stream>>>(Qr, Kr, Vt, AO);
  // out = ao @ w_proj^T : [4096,2048] x [2048,2048]^T, fp32 out
  gemm_bt<true><<<dim3(16, 32), 256, 0, stream>>>(AO, WPROJB, d_out, 4096, 2048, 2048);
}

// Round 3
// 447.045 us; speedup vs baseline: 1.3631x; 1.3631x over previous
//
#include <hip/hip_runtime.h>
#include <stdint.h>

typedef float f32x4 __attribute__((ext_vector_type(4)));
typedef __bf16 bf16x8 __attribute__((ext_vector_type(8)));
typedef unsigned short u16x8 __attribute__((ext_vector_type(8)));

__device__ __forceinline__ unsigned short f2bf(float f) {
  union { float f; unsigned u; } x; x.f = f;
  unsigned r = x.u + 0x7fffu + ((x.u >> 16) & 1u);
  return (unsigned short)(r >> 16);
}
__device__ __forceinline__ float bf2f(unsigned short u) {
  union { unsigned u; float f; } x; x.u = ((unsigned)u) << 16;
  return x.f;
}
__device__ __forceinline__ void async_copy16(void* lds, const void* g) {
  __builtin_amdgcn_global_load_lds(
      (const unsigned int __attribute__((address_space(1)))*)g,
      (unsigned int __attribute__((address_space(3)))*)lds, 16, 0, 0);
}
__device__ __forceinline__ f32x4 mfma16(bf16x8 a, bf16x8 b, f32x4 c) {
  return __builtin_amdgcn_mfma_f32_16x16x32_bf16(a, b, c, 0, 0, 0);
}

// ---------------- fp32 -> bf16 convert ----------------
__global__ __launch_bounds__(256) void cvt_f32_bf16(
    const float* __restrict__ in, unsigned short* __restrict__ out, int n8) {
  int stride = gridDim.x * blockDim.x;
  for (int i = blockIdx.x * blockDim.x + threadIdx.x; i < n8; i += stride) {
    const float4* p = (const float4*)in + (size_t)i * 2;
    float4 a = p[0], b = p[1];
    u16x8 o;
    o[0] = f2bf(a.x); o[1] = f2bf(a.y); o[2] = f2bf(a.z); o[3] = f2bf(a.w);
    o[4] = f2bf(b.x); o[5] = f2bf(b.y); o[6] = f2bf(b.z); o[7] = f2bf(b.w);
    *((u16x8*)out + i) = o;
  }
}

// ---------------- RoPE cos/sin table: [2048][64] float2 (cos,sin) ----------------
__global__ __launch_bounds__(256) void rope_table(float2* __restrict__ cs) {
  int idx = blockIdx.x * 256 + threadIdx.x;   // 2048*64 = 131072
  if (idx >= 2048 * 64) return;
  int t = idx >> 6, j = idx & 63;
  float inv = expf(-0.14391156516026f * (float)j);
  float ang = (float)t * inv;
  cs[idx] = make_float2(cosf(ang), sinf(ang));
}

// ---------------- GEMM: C[M,N] = A[M,K] * Bt[N,K]^T, bf16 in, bf16/f32 out ----------------
#define BM 128
#define BN 128
#define BK 32

template <bool OUT_F32>
__global__ __launch_bounds__(256, 2) void gemm_bt(
    const unsigned short* __restrict__ A, const unsigned short* __restrict__ Bt,
    void* __restrict__ Cout, int M, int N, int K) {
  __shared__ unsigned short sA[2][BM * BK];
  __shared__ unsigned short sB[2][BN * BK];
  const int tid = threadIdx.x;
  const int w = tid >> 6, l = tid & 63;
  const int m0 = blockIdx.y * BM, n0 = blockIdx.x * BN;
  const int wr = w >> 1, wc = w & 1;
  const int g = l >> 4, lr = l & 15;

  f32x4 acc[4][4];
#pragma unroll
  for (int i = 0; i < 4; ++i)
#pragma unroll
    for (int j = 0; j < 4; ++j) acc[i][j] = f32x4{0.f, 0.f, 0.f, 0.f};

  const int rl = l >> 2, ps = l & 3;
  auto stage = [&](int buf, int k0) {
#pragma unroll
    for (int i = 0; i < 2; ++i) {
      int region = w + i * 4;                 // 8 regions of 16 rows each
      int row = region * 16 + rl;
      int s = ps ^ (row & 3);                 // pre-swizzled global source
      async_copy16(&sA[buf][region * 16 * BK],
                   A + (size_t)(m0 + row) * K + k0 + s * 8);
      async_copy16(&sB[buf][region * 16 * BK],
                   Bt + (size_t)(n0 + row) * K + k0 + s * 8);
    }
  };

  stage(0, 0);
  int cur = 0;
  const int NK = K / BK;
  for (int kt = 0; kt < NK; ++kt) {
    asm volatile("s_waitcnt vmcnt(0)" ::: "memory");
    __syncthreads();
    if (kt + 1 < NK) stage(cur ^ 1, (kt + 1) * BK);

    bf16x8 af[4], bfr[4];
#pragma unroll
    for (int mi = 0; mi < 4; ++mi) {
      int row = wr * 64 + mi * 16 + lr;
      af[mi] = *(const bf16x8*)&sA[cur][row * BK + ((g ^ (row & 3)) << 3)];
    }
#pragma unroll
    for (int ni = 0; ni < 4; ++ni) {
      int row = wc * 64 + ni * 16 + lr;
      bfr[ni] = *(const bf16x8*)&sB[cur][row * BK + ((g ^ (row & 3)) << 3)];
    }
#pragma unroll
    for (int mi = 0; mi < 4; ++mi)
#pragma unroll
      for (int ni = 0; ni < 4; ++ni)
        acc[mi][ni] = mfma16(af[mi], bfr[ni], acc[mi][ni]);
    __syncthreads();
    cur ^= 1;
  }

#pragma unroll
  for (int mi = 0; mi < 4; ++mi)
#pragma unroll
    for (int ni = 0; ni < 4; ++ni) {
      int col = n0 + wc * 64 + ni * 16 + lr;
#pragma unroll
      for (int jr = 0; jr < 4; ++jr) {
        int row = m0 + wr * 64 + mi * 16 + g * 4 + jr;
        float v = acc[mi][ni][jr];
        if (OUT_F32)
          ((float*)Cout)[(size_t)row * N + col] = v;
        else
          ((unsigned short*)Cout)[(size_t)row * N + col] = f2bf(v);
      }
    }
}

// ---------------- RoPE + scatter: qkv[4096][6144] -> Q,K [bh][T][128], Vt [bh][128][T] ----------------
__global__ __launch_bounds__(256) void prep_rope(
    const unsigned short* __restrict__ qkv, const float2* __restrict__ cs,
    unsigned short* __restrict__ Q, unsigned short* __restrict__ K,
    unsigned short* __restrict__ Vt) {
  const int tt = blockIdx.x, h = blockIdx.y, b = blockIdx.z;
  const int t0 = tt * 64;
  const int tid = threadIdx.x;
  __shared__ unsigned short vt[64][130];   // +2 pad: conflict-free column reads

#pragma unroll 4
  for (int i = 0; i < 32; ++i) {
    int lin = i * 256 + tid;             // 64 rows x 128 dims
    int r = lin >> 7, j = lin & 127;
    int t = t0 + r;
    int jj = j & 63;
    size_t rowbase = ((size_t)(b * 2048 + t)) * 6144 + h * 128;
    float2 c_s = cs[t * 64 + jj];
    float q1 = bf2f(qkv[rowbase + 2 * jj]);
    float q2 = bf2f(qkv[rowbase + 2 * jj + 1]);
    float k1 = bf2f(qkv[rowbase + 2048 + 2 * jj]);
    float k2 = bf2f(qkv[rowbase + 2048 + 2 * jj + 1]);
    float qo = (j < 64) ? (q1 * c_s.x - q2 * c_s.y) : (q1 * c_s.y + q2 * c_s.x);
    float ko = (j < 64) ? (k1 * c_s.x - k2 * c_s.y) : (k1 * c_s.y + k2 * c_s.x);
    size_t obase = ((size_t)((b * 16 + h) * 2048 + t)) * 128 + j;
    Q[obase] = f2bf(qo);
    K[obase] = f2bf(ko);
    vt[r][j] = qkv[rowbase + 4096 + j];
  }
  __syncthreads();
  size_t vbase = ((size_t)((b * 16 + h) * 128)) * 2048 + t0;
#pragma unroll 4
  for (int i = 0; i < 32; ++i) {
    int lin = i * 256 + tid;
    int d = lin >> 6, c = lin & 63;
    Vt[vbase + (size_t)d * 2048 + c] = vt[c][d];
  }
}

// ---------------- causal flash attention (fold-paired, dbuf, 8 waves) ----------------
// 256 blocks (1/CU): bid -> {xcd=bid&7 -> 4 bh each; qp=bid>>5}. Block processes
// Q-tiles qp and 15-qp (128 rows each) => uniform 34 KV-iterations.
// 8 waves x 16 q-rows; KV tile 64. sK/sV double-buffered (T3 2-phase), sP per-wave.
__global__ __launch_bounds__(512, 2) void attn_fwd(
    const unsigned short* __restrict__ Q, const unsigned short* __restrict__ K,
    const unsigned short* __restrict__ Vt, unsigned short* __restrict__ AO) {
  const int bid = blockIdx.x;
  const int bh = (bid & 7) * 4 + ((bid >> 3) & 3);  // 4 bh per XCD -> L2 reuse
  const int qp = bid >> 5;                          // 0..7
  const int b = bh >> 4, h = bh & 15;
  __shared__ unsigned short sK[2][64 * 128];
  __shared__ unsigned short sV[2][128 * 64];
  __shared__ unsigned short sP[8][16 * 64];
  const int tid = threadIdx.x, w = tid >> 6, l = tid & 63;
  const int g = l >> 4, lr = l & 15;
  const size_t qkbase = (size_t)bh * 2048 * 128;
  const size_t vbase = (size_t)bh * 128 * 2048;
  const float scale = 0.08838834764831845f;  // 1/sqrt(128)

  auto stage = [&](int buf, int kt) {
#pragma unroll
    for (int j = 0; j < 2; ++j) {
      int r = w * 2 + j;                       // 16 issues of 1KB each
      int kv = r * 4 + (l >> 4);               // sK rows: 4 per issue
      int sc = (l & 15) ^ (kv & 15);
      async_copy16(&sK[buf][r * 512],
                   K + qkbase + (size_t)(kt * 64 + kv) * 128 + sc * 8);
      int d = r * 8 + (l >> 3);                // sV rows: 8 per issue
      int sv = (l & 7) ^ (d & 7);
      async_copy16(&sV[buf][r * 512],
                   Vt + vbase + (size_t)d * 2048 + kt * 64 + sv * 8);
    }
  };

  auto process = [&](int qt) {
    const int q0w = qt * 128 + w * 16;
    bf16x8 qf[4];
#pragma unroll
    for (int kc = 0; kc < 4; ++kc)
      qf[kc] = *(const bf16x8*)(Q + qkbase + (size_t)(q0w + lr) * 128 +
                                kc * 32 + g * 8);
    f32x4 of[8];
    float mrow[4], lsum[4];
#pragma unroll
    for (int nd = 0; nd < 8; ++nd) of[nd] = f32x4{0.f, 0.f, 0.f, 0.f};
#pragma unroll
    for (int jr = 0; jr < 4; ++jr) { mrow[jr] = -1e30f; lsum[jr] = 0.f; }

    const int NT = 2 * qt + 2;
    __syncthreads();                 // prior tile's reads done before restage
    stage(0, 0);
    int cur = 0;
    for (int kt = 0; kt < NT; ++kt) {
      asm volatile("s_waitcnt vmcnt(0)" ::: "memory");
      __syncthreads();
      if (kt + 1 < NT) stage(cur ^ 1, kt + 1);   // prefetch hides under compute

      if (kt * 64 <= q0w + 15) {                 // skip fully-masked waves
        // ---- S = Q K^T ----
        f32x4 sacc[4];
#pragma unroll
        for (int ni = 0; ni < 4; ++ni) sacc[ni] = f32x4{0.f, 0.f, 0.f, 0.f};
#pragma unroll
        for (int kc = 0; kc < 4; ++kc)
#pragma unroll
          for (int ni = 0; ni < 4; ++ni) {
            int kv = ni * 16 + lr;
            bf16x8 kf = *(const bf16x8*)&sK[cur][kv * 128 +
                          (((kc * 4 + g) ^ (kv & 15)) << 3)];
            sacc[ni] = mfma16(qf[kc], kf, sacc[ni]);
          }

        // ---- online softmax (16-lane-group parallel) ----
        const bool needmask = (kt * 64 + 63 > q0w);
        float pm[4] = {-1e30f, -1e30f, -1e30f, -1e30f};
#pragma unroll
        for (int ni = 0; ni < 4; ++ni)
#pragma unroll
          for (int jr = 0; jr < 4; ++jr) {
            float sv = sacc[ni][jr] * scale;
            if (needmask) {
              int kvg = kt * 64 + ni * 16 + lr;
              int qg = q0w + g * 4 + jr;
              if (kvg > qg) sv = -1e30f;
            }
            sacc[ni][jr] = sv;
            pm[jr] = fmaxf(pm[jr], sv);
          }
#pragma unroll
        for (int jr = 0; jr < 4; ++jr) {
          float v = pm[jr];
          v = fmaxf(v, __shfl_xor(v, 1));
          v = fmaxf(v, __shfl_xor(v, 2));
          v = fmaxf(v, __shfl_xor(v, 4));
          v = fmaxf(v, __shfl_xor(v, 8));
          float mnew = fmaxf(mrow[jr], v);
          float fac = __expf(mrow[jr] - mnew);
          mrow[jr] = mnew;
          float rsum = 0.f;
#pragma unroll
          for (int ni = 0; ni < 4; ++ni) {
            float p = __expf(sacc[ni][jr] - mnew);
            sacc[ni][jr] = p;
            rsum += p;
          }
          rsum += __shfl_xor(rsum, 1);
          rsum += __shfl_xor(rsum, 2);
          rsum += __shfl_xor(rsum, 4);
          rsum += __shfl_xor(rsum, 8);
          lsum[jr] = lsum[jr] * fac + rsum;
#pragma unroll
          for (int nd = 0; nd < 8; ++nd) of[nd][jr] *= fac;
        }

        // ---- P -> LDS (bf16, swizzled), wave-private ----
#pragma unroll
        for (int ni = 0; ni < 4; ++ni)
#pragma unroll
          for (int jr = 0; jr < 4; ++jr) {
            int q = g * 4 + jr;
            int kv = ni * 16 + lr;
            sP[w][q * 64 + (((kv >> 3) ^ (q & 7)) << 3) + (kv & 7)] =
                f2bf(sacc[ni][jr]);
          }

        // ---- O += P V ----
#pragma unroll
        for (int kc = 0; kc < 2; ++kc) {
          bf16x8 pa = *(const bf16x8*)&sP[w][lr * 64 +
                        (((kc * 4 + g) ^ (lr & 7)) << 3)];
#pragma unroll
          for (int nd = 0; nd < 8; ++nd) {
            int d = nd * 16 + lr;
            bf16x8 vb = *(const bf16x8*)&sV[cur][d * 64 +
                          (((kc * 4 + g) ^ (d & 7)) << 3)];
            of[nd] = mfma16(pa, vb, of[nd]);
          }
        }
      }
      cur ^= 1;
    }

    // ---- epilogue ----
#pragma unroll
    for (int nd = 0; nd < 8; ++nd)
#pragma unroll
      for (int jr = 0; jr < 4; ++jr) {
        int qrow = q0w + g * 4 + jr;
        int d = nd * 16 + lr;
        AO[(size_t)(b * 2048 + qrow) * 2048 + h * 128 + d] =
            f2bf(of[nd][jr] / lsum[jr]);
      }
  };

  process(qp);
  process(15 - qp);
}

// ---------------- launch ----------------
extern "C" void kernel_launch(void* const* d_in, const int* in_sizes, int n_in,
                              void* d_out, int out_size, void* d_ws, size_t ws_size,
                              hipStream_t stream) {
  (void)in_sizes; (void)n_in; (void)out_size; (void)ws_size;
  const float* x = (const float*)d_in[0];
  const float* wqkv = (const float*)d_in[1];
  const float* wproj = (const float*)d_in[2];

  char* ws = (char*)d_ws;
  unsigned short* WPROJB = (unsigned short*)(ws + 0);            //  8.4 MB
  unsigned short* XB     = (unsigned short*)(ws + 8388608);      // 16.8 MB (reused as AO)
  unsigned short* WQKVB  = (unsigned short*)(ws + 25165824);     // 25.2 MB (reused as Q)
  unsigned short* QKV    = (unsigned short*)(ws + 50331648);     // 50.3 MB
  unsigned short* Kr     = (unsigned short*)(ws + 100663296);    // 16.8 MB
  unsigned short* Vt     = (unsigned short*)(ws + 117440512);    // 16.8 MB
  float2*         CS     = (float2*)(ws + 134217728);            //  1.0 MB
  unsigned short* AO = XB;
  unsigned short* Qr = WQKVB;

  rope_table<<<512, 256, 0, stream>>>(CS);
  cvt_f32_bf16<<<2048, 256, 0, stream>>>(x, XB, 8388608 / 8);
  cvt_f32_bf16<<<2048, 256, 0, stream>>>(wqkv, WQKVB, 12582912 / 8);
  cvt_f32_bf16<<<1024, 256, 0, stream>>>(wproj, WPROJB, 4194304 / 8);
  // qkv = x @ w_qkv^T : [4096,2048] x [6144,2048]^T
  gemm_bt<false><<<dim3(48, 32), 256, 0, stream>>>(XB, WQKVB, QKV, 4096, 6144, 2048);
  prep_rope<<<dim3(32, 16, 2), 256, 0, stream>>>(QKV, CS, Qr, Kr, Vt);
  attn_fwd<<<256, 512, 0, stream>>>(Qr, Kr, Vt, AO);
  // out = ao @ w_proj^T : [4096,2048] x [2048,2048]^T, fp32 out
  gemm_bt<true><<<dim3(16, 32), 256, 0, stream>>>(AO, WPROJB, d_out, 4096, 2048, 2048);
}